// Round 3
// baseline (131.210 us; speedup 1.0000x reference)
//
#include <hip/hip_runtime.h>

// RDF loss: all-pairs (N^2) distance histogram (10 unit bins) -> rdf -> MSE.
// Histogram via cumulative compares on d^2 (no sqrt/floor/atomics in hot loop):
// c[k] = #(d2 < ((k+1)dr)^2), k=0..8, plus c[9] = #(d2 <= rmax^2).
// hist_0 = c[0]; hist_b = c[b]-c[b-1]; hist_{nb-1} = c[9]-c[8].
// REFERENCE EMULATION: jax.ops.segment_sum accumulates 1.0f's in fp32 ->
// saturates at 2^24 (adding 1.0 to 16777216.0 rounds back, tie-to-even).
// So ref hist_b = min(C_b, 2^24); we clamp identically in the loss kernel.

#define BLOCK   256
#define NSTRICT 9
#define NCNT    10
#define JTILE   256
#define JSPLIT  32
#define FP32_SAT 16777216u   // 2^24

__global__ __launch_bounds__(BLOCK) void rdf_hist_kernel(
    const float* __restrict__ pc, const int* __restrict__ rmaxp,
    const float* __restrict__ drp, unsigned int* __restrict__ ghist, int n)
{
    __shared__ float sx[JTILE], sy[JTILE], sz[JTILE];
    __shared__ unsigned int sacc[NCNT];

    const int tid  = threadIdx.x;
    const int lane = tid & 63;
    const float rmax  = (float)(*rmaxp);
    const float dr    = *drp;
    const float rmax2 = rmax * rmax;

    float T2[NSTRICT];
    #pragma unroll
    for (int k = 0; k < NSTRICT; ++k) { float t = (float)(k + 1) * dr; T2[k] = t * t; }

    if (tid < NCNT) sacc[tid] = 0u;

    const int i = blockIdx.x * BLOCK + tid;
    float xi, yi, zi;
    if (i < n) { xi = pc[3*i]; yi = pc[3*i+1]; zi = pc[3*i+2]; }
    else       { xi = 3e30f;  yi = 3e30f;     zi = 3e30f; }   // pad -> d2 = inf

    unsigned int c[NCNT];
    #pragma unroll
    for (int k = 0; k < NCNT; ++k) c[k] = 0u;

    const int jchunk = (n + (int)gridDim.y - 1) / (int)gridDim.y;
    const int j0 = blockIdx.y * jchunk;
    const int j1 = min(j0 + jchunk, n);

    for (int jt = j0; jt < j1; jt += JTILE) {
        const int jc = min(JTILE, j1 - jt);
        __syncthreads();
        for (int k = tid; k < JTILE; k += BLOCK) {
            if (k < jc) {
                sx[k] = pc[3*(jt+k)]; sy[k] = pc[3*(jt+k)+1]; sz[k] = pc[3*(jt+k)+2];
            } else {
                sx[k] = -3e30f; sy[k] = -3e30f; sz[k] = -3e30f;
            }
        }
        __syncthreads();
        #pragma unroll 4
        for (int j = 0; j < jc; ++j) {          // uniform loop, LDS broadcast reads
            float dx = xi - sx[j];
            float dy = yi - sy[j];
            float dz = zi - sz[j];
            float d2 = fmaf(dx, dx, fmaf(dy, dy, dz * dz));
            #pragma unroll
            for (int k = 0; k < NSTRICT; ++k)
                c[k] += (unsigned int)__popcll(__ballot(d2 < T2[k]));
            c[NCNT-1] += (unsigned int)__popcll(__ballot(d2 <= rmax2));
        }
    }

    // Every lane of a wave holds the wave's totals; lane 0 contributes them.
    __syncthreads();
    if (lane == 0) {
        #pragma unroll
        for (int k = 0; k < NCNT; ++k) atomicAdd(&sacc[k], c[k]);
    }
    __syncthreads();
    if (tid < NCNT) atomicAdd(&ghist[tid], sacc[tid]);
}

__global__ void rdf_loss_kernel(const unsigned int* __restrict__ ghist,
                                const float* __restrict__ target,
                                const int* __restrict__ rmaxp,
                                const float* __restrict__ drp,
                                float* __restrict__ out, int n, int mt)
{
    if (threadIdx.x != 0 || blockIdx.x != 0) return;
    const float PI = 3.14159265358979323846f;
    const float rmax = (float)(*rmaxp);
    const float dr   = *drp;
    int nbins = (int)roundf(rmax / dr);
    if (nbins > NCNT) nbins = NCNT;   // structural cap (problem has nbins=10)
    const float density = (float)n / (4.0f / 3.0f * PI * rmax * rmax * rmax);
    const int m = (mt < nbins) ? mt : nbins;
    float acc = 0.0f;
    for (int b = 0; b < m; ++b) {
        unsigned int hb;
        if (b == 0)              hb = ghist[0];
        else if (b == nbins - 1) hb = ghist[NCNT-1] - ghist[b-1];
        else                     hb = ghist[b] - ghist[b-1];
        if (hb > FP32_SAT) hb = FP32_SAT;   // fp32 segment_sum saturation emulation
        float r_mid = ((float)b + 0.5f) * dr;
        float ideal = 4.0f * PI * r_mid * r_mid * dr * density * (float)n;
        float rdf  = (ideal != 0.0f) ? ((float)hb / ideal) : 0.0f;
        float diff = rdf - target[b];
        acc = fmaf(diff, diff, acc);
    }
    out[0] = acc / (float)m;
}

extern "C" void kernel_launch(void* const* d_in, const int* in_sizes, int n_in,
                              void* d_out, int out_size, void* d_ws, size_t ws_size,
                              hipStream_t stream)
{
    const float* pc      = (const float*)d_in[0];
    const float* target  = (const float*)d_in[1];
    const int*   rmaxp   = (const int*)d_in[2];
    const float* drp     = (const float*)d_in[3];
    const int n  = in_sizes[0] / 3;
    const int mt = in_sizes[1];

    unsigned int* ghist = (unsigned int*)d_ws;
    hipMemsetAsync(ghist, 0, NCNT * sizeof(unsigned int), stream);

    dim3 grid((n + BLOCK - 1) / BLOCK, JSPLIT);
    rdf_hist_kernel<<<grid, BLOCK, 0, stream>>>(pc, rmaxp, drp, ghist, n);
    rdf_loss_kernel<<<1, 64, 0, stream>>>(ghist, target, rmaxp, drp,
                                          (float*)d_out, n, mt);
}

// Round 4
// 124.885 us; speedup vs baseline: 1.0506x; 1.0506x over previous
//
#include <hip/hip_runtime.h>

// RDF loss: all-pairs distance histogram (10 unit bins) -> rdf -> MSE.
// Triangular tiling: ordered counts C[k] = 2*C_strict[k] + N (diag d2=0 is in
// every cumulative bin). Cumulative compares on d2 (no sqrt/floor):
//   c[k] = #(d2 < ((k+1)dr)^2) k=0..8,  c[9] = #(d2 <= rmax^2)  [strict i<j]
// d2 via Gram form (matches reference arithmetic): d2 = sqi + sqj - 2*dot.
// Per-lane carry-add counters, wave shfl_xor reduce, LDS combine, 10 padded
// global atomic slots. Reference emulation: fp32 segment_sum saturates at
// 2^24 -> clamp each bin count in the loss kernel.

#define BLOCK    128
#define NSTRICT  9
#define NCNT     10
#define SLOT     16          // u32 stride between bins (64B -> separate lines)
#define FP32_SAT 16777216u   // 2^24

__device__ __forceinline__ int row_start(int r, int T) {
    return r * T - ((r * (r - 1)) >> 1);
}

__global__ __launch_bounds__(BLOCK) void rdf_hist_kernel(
    const float* __restrict__ pc, const int* __restrict__ rmaxp,
    const float* __restrict__ drp, unsigned int* __restrict__ ghist,
    int n, int T)
{
    __shared__ float4 sj[BLOCK];
    __shared__ unsigned int sacc[NCNT];

    const int tid = threadIdx.x;
    const int bid = (int)blockIdx.x;

    // decode triangular pair (ti <= tj) from bid
    const float tf = (float)T;
    float disc = (2.0f * tf + 1.0f) * (2.0f * tf + 1.0f) - 8.0f * (float)bid;
    int ti = (int)((2.0f * tf + 1.0f - sqrtf(disc)) * 0.5f);
    if (ti >= T) ti = T - 1;
    if (ti < 0) ti = 0;
    while (ti > 0 && row_start(ti, T) > bid) --ti;
    while (row_start(ti + 1, T) <= bid) ++ti;
    const int tj = ti + (bid - row_start(ti, T));

    const float rmax  = (float)(*rmaxp);
    const float dr    = *drp;
    const float rmax2 = rmax * rmax;
    float T2[NSTRICT];
    #pragma unroll
    for (int k = 0; k < NSTRICT; ++k) { float t = (float)(k + 1) * dr; T2[k] = t * t; }

    if (tid < NCNT) sacc[tid] = 0u;

    {   // stage j tile as float4(x,y,z,sq); pads get sq=3e30 -> never counted
        const int j = tj * BLOCK + tid;
        float x = 0.f, y = 0.f, z = 0.f, s = 3.0e30f;
        if (j < n) { x = pc[3*j]; y = pc[3*j+1]; z = pc[3*j+2]; s = x*x + y*y + z*z; }
        sj[tid] = make_float4(x, y, z, s);
    }

    const int i = ti * BLOCK + tid;
    float xi = 0.f, yi = 0.f, zi = 0.f, sqi = 3.0e30f;
    if (i < n) { xi = pc[3*i]; yi = pc[3*i+1]; zi = pc[3*i+2]; sqi = xi*xi + yi*yi + zi*zi; }
    const float m2x = -2.0f * xi, m2y = -2.0f * yi, m2z = -2.0f * zi;

    __syncthreads();

    unsigned int c[NCNT];
    #pragma unroll
    for (int k = 0; k < NCNT; ++k) c[k] = 0u;

    if (ti == tj) {
        #pragma unroll 8
        for (int j = 0; j < BLOCK; ++j) {
            float4 p = sj[j];
            float d2 = sqi + p.w;
            d2 = fmaf(m2x, p.x, d2);
            d2 = fmaf(m2y, p.y, d2);
            d2 = fmaf(m2z, p.z, d2);
            d2 = (j > tid) ? d2 : 3.0e30f;   // strict upper triangle only
            #pragma unroll
            for (int k = 0; k < NSTRICT; ++k) c[k] += (unsigned int)(d2 < T2[k]);
            c[NCNT-1] += (unsigned int)(d2 <= rmax2);
        }
    } else {
        #pragma unroll 8
        for (int j = 0; j < BLOCK; ++j) {
            float4 p = sj[j];
            float d2 = sqi + p.w;
            d2 = fmaf(m2x, p.x, d2);
            d2 = fmaf(m2y, p.y, d2);
            d2 = fmaf(m2z, p.z, d2);
            #pragma unroll
            for (int k = 0; k < NSTRICT; ++k) c[k] += (unsigned int)(d2 < T2[k]);
            c[NCNT-1] += (unsigned int)(d2 <= rmax2);
        }
    }

    // wave butterfly reduce, then one LDS combine, then 10 global atomics/block
    #pragma unroll
    for (int k = 0; k < NCNT; ++k) {
        unsigned int v = c[k];
        #pragma unroll
        for (int m = 32; m >= 1; m >>= 1) v += (unsigned int)__shfl_xor((int)v, m, 64);
        c[k] = v;
    }
    if ((tid & 63) == 0) {
        #pragma unroll
        for (int k = 0; k < NCNT; ++k) atomicAdd(&sacc[k], c[k]);
    }
    __syncthreads();
    if (tid < NCNT) atomicAdd(&ghist[tid * SLOT], sacc[tid]);
}

__global__ void rdf_loss_kernel(const unsigned int* __restrict__ ghist,
                                const float* __restrict__ target,
                                const int* __restrict__ rmaxp,
                                const float* __restrict__ drp,
                                float* __restrict__ out, int n, int mt)
{
    if (threadIdx.x != 0 || blockIdx.x != 0) return;
    const float PI = 3.14159265358979323846f;
    const float rmax = (float)(*rmaxp);
    const float dr   = *drp;
    int nbins = (int)roundf(rmax / dr);
    if (nbins > NCNT) nbins = NCNT;
    const float density = (float)n / (4.0f / 3.0f * PI * rmax * rmax * rmax);
    const int m = (mt < nbins) ? mt : nbins;

    unsigned int C[NCNT];
    #pragma unroll
    for (int k = 0; k < NCNT; ++k)
        C[k] = 2u * ghist[k * SLOT] + (unsigned int)n;   // ordered = 2*strict + diag

    float acc = 0.0f;
    for (int b = 0; b < m; ++b) {
        unsigned int hb;
        if (b == 0)              hb = C[0];
        else if (b == nbins - 1) hb = C[NCNT-1] - C[b-1];
        else                     hb = C[b] - C[b-1];
        if (hb > FP32_SAT) hb = FP32_SAT;   // fp32 segment_sum saturation
        float r_mid = ((float)b + 0.5f) * dr;
        float ideal = 4.0f * PI * r_mid * r_mid * dr * density * (float)n;
        float rdf  = (ideal != 0.0f) ? ((float)hb / ideal) : 0.0f;
        float diff = rdf - target[b];
        acc = fmaf(diff, diff, acc);
    }
    out[0] = acc / (float)m;
}

extern "C" void kernel_launch(void* const* d_in, const int* in_sizes, int n_in,
                              void* d_out, int out_size, void* d_ws, size_t ws_size,
                              hipStream_t stream)
{
    const float* pc     = (const float*)d_in[0];
    const float* target = (const float*)d_in[1];
    const int*   rmaxp  = (const int*)d_in[2];
    const float* drp    = (const float*)d_in[3];
    const int n  = in_sizes[0] / 3;
    const int mt = in_sizes[1];

    unsigned int* ghist = (unsigned int*)d_ws;
    hipMemsetAsync(ghist, 0, NCNT * SLOT * sizeof(unsigned int), stream);

    const int T = (n + BLOCK - 1) / BLOCK;
    const int nblocks = T * (T + 1) / 2;
    rdf_hist_kernel<<<nblocks, BLOCK, 0, stream>>>(pc, rmaxp, drp, ghist, n, T);
    rdf_loss_kernel<<<1, 64, 0, stream>>>(ghist, target, rmaxp, drp,
                                          (float*)d_out, n, mt);
}

// Round 5
// 45.107 us; speedup vs baseline: 2.9089x; 2.7686x over previous
//
#include <hip/hip_runtime.h>

// RDF loss: all-pairs distance histogram (10 unit bins) -> rdf -> MSE.
// Triangular 256-tiles (ordered hist = 2*strict + N diag counts in bin 0).
// Inner loop: Gram-form d2 (1 ds_read_b128 broadcast/j) -> v_sqrt -> v_cvt
// (trunc==floor) -> clamp to 15 -> ds_add_u32 into per-thread private LDS row
// (stride 17 words -> 2 lanes/bank, conflict-free). Trash bins 10..15 absorb
// d>rmax, padding points, and masked diagonal (d2=3e30). No global atomics:
// per-block partials written non-atomically, reduced in a fused loss kernel.
// Reference emulation: fp32 segment_sum saturates at 2^24 -> clamp per bin.

#define BLOCK    256
#define HPAD     17          // private row stride in words
#define NROWB    16          // bins stored per row (10 real + 6 trash)
#define NB       10
#define SLOT     16          // u32 stride between block-partial rows
#define FP32_SAT 16777216u   // 2^24

__device__ __forceinline__ int row_start(int r, int T) {
    return r * T - ((r * (r - 1)) >> 1);
}

__global__ __launch_bounds__(BLOCK) void rdf_hist_kernel(
    const float* __restrict__ pc, const int* __restrict__ rmaxp,
    const float* __restrict__ drp, unsigned int* __restrict__ part,
    int n, int T)
{
    __shared__ float4 sj[BLOCK];
    __shared__ unsigned int lh[BLOCK * HPAD];
    __shared__ unsigned int sacc[NB];

    const int tid = threadIdx.x;
    const int bid = (int)blockIdx.x;

    // decode triangular pair (ti <= tj)
    const float tf = (float)T;
    float disc = (2.f*tf + 1.f)*(2.f*tf + 1.f) - 8.f*(float)bid;
    int ti = (int)((2.f*tf + 1.f - sqrtf(disc)) * 0.5f);
    ti = max(0, min(ti, T - 1));
    while (ti > 0 && row_start(ti, T) > bid) --ti;
    while (row_start(ti + 1, T) <= bid) ++ti;
    const int tj = ti + (bid - row_start(ti, T));

    const float inv_dr = 1.0f / (*drp);

    // zero private hist row + shared accumulators
    #pragma unroll
    for (int k = 0; k < HPAD; ++k) lh[tid * HPAD + k] = 0u;
    if (tid < NB) sacc[tid] = 0u;

    {   // stage j tile as float4(x,y,z,|p|^2); pads get 3e30 -> trash bin
        const int j = tj * BLOCK + tid;
        float x = 0.f, y = 0.f, z = 0.f, s = 3.0e30f;
        if (j < n) { x = pc[3*j]; y = pc[3*j+1]; z = pc[3*j+2]; s = x*x + y*y + z*z; }
        sj[tid] = make_float4(x, y, z, s);
    }
    const int i = ti * BLOCK + tid;
    float xi = 0.f, yi = 0.f, zi = 0.f, sqi = 3.0e30f;
    if (i < n) { xi = pc[3*i]; yi = pc[3*i+1]; zi = pc[3*i+2]; sqi = xi*xi + yi*yi + zi*zi; }
    const float m2x = -2.f*xi, m2y = -2.f*yi, m2z = -2.f*zi;

    __syncthreads();

    unsigned int* myrow = &lh[tid * HPAD];

    if (ti == tj) {
        #pragma unroll 8
        for (int j = 0; j < BLOCK; ++j) {
            float4 p = sj[j];
            float d2 = sqi + p.w;
            d2 = fmaf(m2x, p.x, d2);
            d2 = fmaf(m2y, p.y, d2);
            d2 = fmaf(m2z, p.z, d2);
            d2 = (j > tid) ? d2 : 3.0e30f;          // strict upper triangle
            float d = __builtin_amdgcn_sqrtf(d2) * inv_dr;
            unsigned int b = (unsigned int)fminf(d, (float)(NROWB - 1));
            atomicAdd(&myrow[b], 1u);               // ds_add_u32, no return
        }
    } else {
        #pragma unroll 8
        for (int j = 0; j < BLOCK; ++j) {
            float4 p = sj[j];
            float d2 = sqi + p.w;
            d2 = fmaf(m2x, p.x, d2);
            d2 = fmaf(m2y, p.y, d2);
            d2 = fmaf(m2z, p.z, d2);
            float d = __builtin_amdgcn_sqrtf(d2) * inv_dr;
            unsigned int b = (unsigned int)fminf(d, (float)(NROWB - 1));
            atomicAdd(&myrow[b], 1u);
        }
    }

    // readback my private row (bins 0..9), wave butterfly, LDS combine,
    // then ONE non-atomic partial row per block (no global atomics).
    unsigned int v[NB];
    #pragma unroll
    for (int k = 0; k < NB; ++k) v[k] = myrow[k];
    #pragma unroll
    for (int k = 0; k < NB; ++k) {
        unsigned int s = v[k];
        #pragma unroll
        for (int m = 32; m >= 1; m >>= 1) s += (unsigned int)__shfl_xor((int)s, m, 64);
        v[k] = s;
    }
    if ((tid & 63) == 0) {
        #pragma unroll
        for (int k = 0; k < NB; ++k) atomicAdd(&sacc[k], v[k]);
    }
    __syncthreads();
    if (tid < NB) part[bid * SLOT + tid] = sacc[tid];
}

__global__ __launch_bounds__(BLOCK) void rdf_reduce_loss_kernel(
    const unsigned int* __restrict__ part, const float* __restrict__ target,
    const int* __restrict__ rmaxp, const float* __restrict__ drp,
    float* __restrict__ out, int n, int mt, int nblocks)
{
    __shared__ unsigned int sacc[NB];
    const int tid = threadIdx.x;
    if (tid < NB) sacc[tid] = 0u;
    __syncthreads();

    unsigned int a[NB];
    #pragma unroll
    for (int k = 0; k < NB; ++k) a[k] = 0u;
    for (int i = tid; i < nblocks; i += BLOCK) {
        #pragma unroll
        for (int k = 0; k < NB; ++k) a[k] += part[i * SLOT + k];
    }
    #pragma unroll
    for (int k = 0; k < NB; ++k) {
        unsigned int s = a[k];
        #pragma unroll
        for (int m = 32; m >= 1; m >>= 1) s += (unsigned int)__shfl_xor((int)s, m, 64);
        if ((tid & 63) == 0) atomicAdd(&sacc[k], s);
    }
    __syncthreads();

    if (tid == 0) {
        const float PI = 3.14159265358979323846f;
        const float rmax = (float)(*rmaxp);
        const float dr   = *drp;
        int nbins = (int)roundf(rmax / dr);
        if (nbins > NB) nbins = NB;
        const float density = (float)n / (4.0f / 3.0f * PI * rmax * rmax * rmax);
        const int m = (mt < nbins) ? mt : nbins;
        float acc = 0.0f;
        for (int b = 0; b < m; ++b) {
            unsigned int hb = 2u * sacc[b] + ((b == 0) ? (unsigned int)n : 0u);
            if (hb > FP32_SAT) hb = FP32_SAT;   // fp32 segment_sum saturation
            float r_mid = ((float)b + 0.5f) * dr;
            float ideal = 4.0f * PI * r_mid * r_mid * dr * density * (float)n;
            float rdf  = (ideal != 0.0f) ? ((float)hb / ideal) : 0.0f;
            float diff = rdf - target[b];
            acc = fmaf(diff, diff, acc);
        }
        out[0] = acc / (float)m;
    }
}

extern "C" void kernel_launch(void* const* d_in, const int* in_sizes, int n_in,
                              void* d_out, int out_size, void* d_ws, size_t ws_size,
                              hipStream_t stream)
{
    const float* pc     = (const float*)d_in[0];
    const float* target = (const float*)d_in[1];
    const int*   rmaxp  = (const int*)d_in[2];
    const float* drp    = (const float*)d_in[3];
    const int n  = in_sizes[0] / 3;
    const int mt = in_sizes[1];

    unsigned int* part = (unsigned int*)d_ws;
    const int T = (n + BLOCK - 1) / BLOCK;
    const int nblocks = T * (T + 1) / 2;

    rdf_hist_kernel<<<nblocks, BLOCK, 0, stream>>>(pc, rmaxp, drp, part, n, T);
    rdf_reduce_loss_kernel<<<1, BLOCK, 0, stream>>>(part, target, rmaxp, drp,
                                                    (float*)d_out, n, mt, nblocks);
}

// Round 6
// 40.498 us; speedup vs baseline: 3.2399x; 1.1138x over previous
//
#include <hip/hip_runtime.h>

// RDF loss: all-pairs distance histogram (10 unit bins) -> rdf -> MSE.
// Triangular 256-tiles (ordered hist = 2*strict + N diag in bin 0).
// Inner loop is pure VALU + one broadcast ds_read_b128 per j:
//   d2 (Gram form, coords pre-scaled by 1/dr) -> v_sqrt -> v_cvt_u32 (sat)
//   -> min(b,10) -> cnt += 1ull<<(6b)   [u64 = 10 bin fields x 6 bits,
//   flushed to u32 counters every 32 iters; field 10 @bits60..63 is trash,
//   its overflow falls off the register top harmlessly]
// No LDS atomics (round-5 bottleneck: ds_add on the per-CU LDS pipe).
// Per-block partials written non-atomically; fused reduce+loss kernel.
// Reference emulation: fp32 segment_sum saturates at 2^24 -> clamp per bin.

#define BLOCK    256
#define NB       10
#define SLOT     16          // u32 stride between block-partial rows
#define FP32_SAT 16777216u   // 2^24

__device__ __forceinline__ int row_start(int r, int T) {
    return r * T - ((r * (r - 1)) >> 1);
}

template <bool DIAG>
__device__ __forceinline__ void tile_loop(const float4* __restrict__ sj,
                                          float sqi, float m2x, float m2y, float m2z,
                                          int tid, unsigned int* c)
{
    for (int jc = 0; jc < BLOCK; jc += 32) {
        unsigned long long cnt = 0ull;
        #pragma unroll
        for (int jj = 0; jj < 32; ++jj) {
            const int j = jc + jj;
            float4 p = sj[j];
            float d2 = sqi + p.w;
            d2 = fmaf(m2x, p.x, d2);
            d2 = fmaf(m2y, p.y, d2);
            d2 = fmaf(m2z, p.z, d2);
            if (DIAG) d2 = (j > tid) ? d2 : 3.0e30f;   // strict upper triangle
            float d = __builtin_amdgcn_sqrtf(d2);
            unsigned int b = (unsigned int)d;           // v_cvt_u32_f32: saturates, NaN->0
            b = min(b, 10u);                            // 10 = trash field
            cnt += 1ull << (b * 6u);
        }
        #pragma unroll
        for (int k = 0; k < NB; ++k)
            c[k] += (unsigned int)(cnt >> (6 * k)) & 63u;
    }
}

__global__ __launch_bounds__(BLOCK) void rdf_hist_kernel(
    const float* __restrict__ pc, const int* __restrict__ rmaxp,
    const float* __restrict__ drp, unsigned int* __restrict__ part,
    int n, int T)
{
    __shared__ float4 sj[BLOCK];
    __shared__ unsigned int sacc[NB];

    const int tid = threadIdx.x;
    const int bid = (int)blockIdx.x;

    // decode triangular tile pair (ti <= tj)
    const float tf = (float)T;
    float disc = (2.f*tf + 1.f)*(2.f*tf + 1.f) - 8.f*(float)bid;
    int ti = (int)((2.f*tf + 1.f - sqrtf(disc)) * 0.5f);
    ti = max(0, min(ti, T - 1));
    while (ti > 0 && row_start(ti, T) > bid) --ti;
    while (row_start(ti + 1, T) <= bid) ++ti;
    const int tj = ti + (bid - row_start(ti, T));

    const float inv_dr = 1.0f / (*drp);

    if (tid < NB) sacc[tid] = 0u;

    {   // stage j tile, coords pre-scaled by 1/dr; pads finite & far (-3e4)
        const int j = tj * BLOCK + tid;
        float x = -3.0e4f, y = -3.0e4f, z = -3.0e4f;
        if (j < n) { x = pc[3*j] * inv_dr; y = pc[3*j+1] * inv_dr; z = pc[3*j+2] * inv_dr; }
        sj[tid] = make_float4(x, y, z, x*x + y*y + z*z);
    }
    const int i = ti * BLOCK + tid;
    float xi = 3.0e4f, yi = 3.0e4f, zi = 3.0e4f;   // i-pads opposite sign to j-pads
    if (i < n) { xi = pc[3*i] * inv_dr; yi = pc[3*i+1] * inv_dr; zi = pc[3*i+2] * inv_dr; }
    const float sqi = xi*xi + yi*yi + zi*zi;
    const float m2x = -2.f*xi, m2y = -2.f*yi, m2z = -2.f*zi;

    __syncthreads();

    unsigned int c[NB];
    #pragma unroll
    for (int k = 0; k < NB; ++k) c[k] = 0u;

    if (ti == tj) tile_loop<true >(sj, sqi, m2x, m2y, m2z, tid, c);
    else          tile_loop<false>(sj, sqi, m2x, m2y, m2z, tid, c);

    // wave butterfly reduce -> LDS combine -> one non-atomic partial row/block
    #pragma unroll
    for (int k = 0; k < NB; ++k) {
        unsigned int s = c[k];
        #pragma unroll
        for (int m = 32; m >= 1; m >>= 1) s += (unsigned int)__shfl_xor((int)s, m, 64);
        c[k] = s;
    }
    if ((tid & 63) == 0) {
        #pragma unroll
        for (int k = 0; k < NB; ++k) atomicAdd(&sacc[k], c[k]);
    }
    __syncthreads();
    if (tid < NB) part[bid * SLOT + tid] = sacc[tid];
}

__global__ __launch_bounds__(BLOCK) void rdf_reduce_loss_kernel(
    const unsigned int* __restrict__ part, const float* __restrict__ target,
    const int* __restrict__ rmaxp, const float* __restrict__ drp,
    float* __restrict__ out, int n, int mt, int nblocks)
{
    __shared__ unsigned int sacc[NB];
    const int tid = threadIdx.x;
    if (tid < NB) sacc[tid] = 0u;
    __syncthreads();

    unsigned int a[NB];
    #pragma unroll
    for (int k = 0; k < NB; ++k) a[k] = 0u;
    for (int i = tid; i < nblocks; i += BLOCK) {
        #pragma unroll
        for (int k = 0; k < NB; ++k) a[k] += part[i * SLOT + k];
    }
    #pragma unroll
    for (int k = 0; k < NB; ++k) {
        unsigned int s = a[k];
        #pragma unroll
        for (int m = 32; m >= 1; m >>= 1) s += (unsigned int)__shfl_xor((int)s, m, 64);
        if ((tid & 63) == 0) atomicAdd(&sacc[k], s);
    }
    __syncthreads();

    if (tid == 0) {
        const float PI = 3.14159265358979323846f;
        const float rmax = (float)(*rmaxp);
        const float dr   = *drp;
        int nbins = (int)roundf(rmax / dr);
        if (nbins > NB) nbins = NB;
        const float density = (float)n / (4.0f / 3.0f * PI * rmax * rmax * rmax);
        const int m = (mt < nbins) ? mt : nbins;
        float acc = 0.0f;
        for (int b = 0; b < m; ++b) {
            unsigned int hb = 2u * sacc[b] + ((b == 0) ? (unsigned int)n : 0u);
            if (hb > FP32_SAT) hb = FP32_SAT;   // fp32 segment_sum saturation
            float r_mid = ((float)b + 0.5f) * dr;
            float ideal = 4.0f * PI * r_mid * r_mid * dr * density * (float)n;
            float rdf  = (ideal != 0.0f) ? ((float)hb / ideal) : 0.0f;
            float diff = rdf - target[b];
            acc = fmaf(diff, diff, acc);
        }
        out[0] = acc / (float)m;
    }
}

extern "C" void kernel_launch(void* const* d_in, const int* in_sizes, int n_in,
                              void* d_out, int out_size, void* d_ws, size_t ws_size,
                              hipStream_t stream)
{
    const float* pc     = (const float*)d_in[0];
    const float* target = (const float*)d_in[1];
    const int*   rmaxp  = (const int*)d_in[2];
    const float* drp    = (const float*)d_in[3];
    const int n  = in_sizes[0] / 3;
    const int mt = in_sizes[1];

    unsigned int* part = (unsigned int*)d_ws;
    const int T = (n + BLOCK - 1) / BLOCK;
    const int nblocks = T * (T + 1) / 2;

    rdf_hist_kernel<<<nblocks, BLOCK, 0, stream>>>(pc, rmaxp, drp, part, n, T);
    rdf_reduce_loss_kernel<<<1, BLOCK, 0, stream>>>(part, target, rmaxp, drp,
                                                    (float*)d_out, n, mt, nblocks);
}